// Round 2
// baseline (215.914 us; speedup 1.0000x reference)
//
#include <hip/hip_runtime.h>
#include <hip/hip_bf16.h>
#include <stdint.h>

// EncoderBlock: B=8, S=1024, D=512, H=12, HS=42 (padded to 64 for GEMM).
// Only batch 0's attention is used (reference quirk: attn[0] + x).

typedef unsigned short u16;
typedef __attribute__((ext_vector_type(8))) short short8;  // 8 bf16 = 4 VGPRs
typedef __attribute__((ext_vector_type(4))) float f32x4;

__device__ __forceinline__ u16 f2bf(float f) {
  union { float f; unsigned u; } x; x.f = f;
  return (u16)((x.u + 0x7FFFu + ((x.u >> 16) & 1u)) >> 16);  // RNE
}
__device__ __forceinline__ float bf2f(u16 u) {
  union { unsigned u; float f; } x; x.u = ((unsigned)u) << 16;
  return x.f;
}

// async global->LDS, 16B per lane; LDS dest is wave-uniform base + lane*16.
__device__ __forceinline__ void gload_lds16(const u16* g, u16* l) {
  __builtin_amdgcn_global_load_lds(
      (__attribute__((address_space(1))) void*)g,
      (__attribute__((address_space(3))) void*)l, 16, 0, 0);
}

__device__ __forceinline__ float wred_sum(float v) {
#pragma unroll
  for (int off = 32; off > 0; off >>= 1) v += __shfl_xor(v, off, 64);
  return v;
}
__device__ __forceinline__ float wred_max(float v) {
#pragma unroll
  for (int off = 32; off > 0; off >>= 1) v = fmaxf(v, __shfl_xor(v, off, 64));
  return v;
}

#define MFMA16x16(a, b, c) __builtin_amdgcn_mfma_f32_16x16x32_bf16(a, b, c, 0, 0, 0)

// ===========================================================================
// 8-phase 256x256 GEMM (HK-style schedule, plain HIP).
// C[m][n] = sum_k A[m][k]*Bt[n][k]. M%256==0, N%256==0, K%64==0.
// 512 threads = 8 waves (wm = w>>2 in {0,1}, wn = w&3).
// Wave output rows: {wm*64..+63} u {128+wm*64..+63}; cols {wn*32..+31} u {128+wn*32..+31}.
// LDS: 2 buf x 4 halves (A0,B0,B1,A1) x 16KB = 128KB, XOR-swizzled:
//   16B-granule g_phys = g_log ^ (row&7)  (involution; applied on stage SOURCE
//   and on ds_read address; LDS dest of global_load_lds stays linear).
// Per K-tile (BK=64): 3 sync phases, counted vmcnt(4) (never 0 in loop).
// ===========================================================================
enum { G8_GELU = 0, G8_F32 = 1 };

template <int EP>
__device__ __forceinline__ void read_af8(short8 (&af)[8], const u16* half,
                                         int aBase, int s0, int s1) {
  const char* hc = (const char*)half;
#pragma unroll
  for (int mi = 0; mi < 4; ++mi) {
    af[mi * 2 + 0] = *(const short8*)(hc + aBase + mi * 2048 + s0);
    af[mi * 2 + 1] = *(const short8*)(hc + aBase + mi * 2048 + s1);
  }
}
template <int EP>
__device__ __forceinline__ void read_bf4(short8 (&bf)[4], const u16* half,
                                         int bBase, int s0, int s1) {
  const char* hc = (const char*)half;
#pragma unroll
  for (int ni = 0; ni < 2; ++ni) {
    bf[ni * 2 + 0] = *(const short8*)(hc + bBase + ni * 2048 + s0);
    bf[ni * 2 + 1] = *(const short8*)(hc + bBase + ni * 2048 + s1);
  }
}
template <int MH, int NH>
__device__ __forceinline__ void do_mfma16(f32x4 (&acc)[8][4],
                                          const short8 (&af)[8],
                                          const short8 (&bf)[4]) {
#pragma unroll
  for (int mi = 0; mi < 4; ++mi)
#pragma unroll
    for (int ni = 0; ni < 2; ++ni)
#pragma unroll
      for (int ks = 0; ks < 2; ++ks)
        acc[MH * 4 + mi][NH * 2 + ni] =
            MFMA16x16(af[mi * 2 + ks], bf[ni * 2 + ks], acc[MH * 4 + mi][NH * 2 + ni]);
}

// stage one 128x64 half-tile: 512 threads x 2 loads x 16B; linear LDS dest,
// inverse-swizzled global source. src = panel base (row 0, k-col 0 of window).
__device__ __forceinline__ void stage_half(const u16* src, int ld, u16* halfdst,
                                           int w, int l) {
  const int r0 = w * 8 + (l >> 3);
  const int ce = ((l & 7) ^ (l >> 3)) * 8;  // swizzled source col (elements)
  gload_lds16(src + (long)r0 * ld + ce, halfdst + w * 512);
  gload_lds16(src + (long)(r0 + 64) * ld + ce, halfdst + (8 + w) * 512);
}

#define H_A0 0
#define H_B0 1
#define H_B1 2
#define H_A1 3

template <int EP>
__launch_bounds__(512, 2)
__global__ void gemm8(const u16* __restrict__ A, int lda, long sAz,
                      const u16* __restrict__ Bt, int ldb, long sBz,
                      void* __restrict__ Cv, int ldc, long sCz, int K,
                      const float* __restrict__ bias) {
  __shared__ u16 lds[2 * 4 * 8192];  // 128 KB
  const int z = blockIdx.z;
  const u16* Ab = A + (long)z * sAz;
  const u16* Bb = Bt + (long)z * sBz;
  const int m0 = blockIdx.x * 256;
  const int n0 = blockIdx.y * 256;
  const int tid = threadIdx.x;
  const int w = tid >> 6;
  const int l = tid & 63;
  const int wm = w >> 2;
  const int wn = w & 3;
  const int NT = K >> 6;

  // ds_read bases (byte offsets within a 16KB half)
  const int aBase = (wm * 64 + (l & 15)) * 128;
  const int bBase = (wn * 32 + (l & 15)) * 128;
  const int s0 = (((l >> 4)) ^ (l & 7)) * 16;      // ks=0 granule (swizzled)
  const int s1 = ((4 + (l >> 4)) ^ (l & 7)) * 16;  // ks=1

  f32x4 acc[8][4];
#pragma unroll
  for (int i = 0; i < 8; ++i)
#pragma unroll
    for (int j = 0; j < 4; ++j) acc[i][j] = (f32x4){0.f, 0.f, 0.f, 0.f};

  short8 af[8], bf0[4], bf1[4];

  // prologue: stage tile 0 (issue order A0,B0,B1,A1 = steady-state order)
  stage_half(Ab + (long)m0 * lda, lda, lds + H_A0 * 8192, w, l);
  stage_half(Bb + (long)n0 * ldb, ldb, lds + H_B0 * 8192, w, l);
  stage_half(Bb + (long)(n0 + 128) * ldb, ldb, lds + H_B1 * 8192, w, l);
  stage_half(Ab + (long)(m0 + 128) * lda, lda, lds + H_A1 * 8192, w, l);

  for (int t = 0; t < NT; ++t) {
    u16* cur = lds + (t & 1) * 32768;
    u16* nxt = lds + ((t & 1) ^ 1) * 32768;
    const int tn = (t + 1 == NT) ? 0 : (t + 1);  // wrap-stage: uniform vmcnt
    const u16* An = Ab + tn * 64;
    const u16* Bn = Bb + tn * 64;

    // ---- phase 0: needs A0,B0 of tile t ----
    asm volatile("s_waitcnt vmcnt(4)" ::: "memory");
    __builtin_amdgcn_s_barrier();
    __builtin_amdgcn_sched_barrier(0);
    read_af8<EP>(af, cur + H_A0 * 8192, aBase, s0, s1);
    read_bf4<EP>(bf0, cur + H_B0 * 8192, bBase, s0, s1);
    stage_half(An + (long)m0 * lda, lda, nxt + H_A0 * 8192, w, l);
    asm volatile("s_waitcnt lgkmcnt(0)" ::: "memory");
    __builtin_amdgcn_sched_barrier(0);
    __builtin_amdgcn_s_setprio(1);
    do_mfma16<0, 0>(acc, af, bf0);
    __builtin_amdgcn_s_setprio(0);

    // ---- phase 1: needs B1 of tile t ----
    asm volatile("s_waitcnt vmcnt(4)" ::: "memory");
    __builtin_amdgcn_s_barrier();
    __builtin_amdgcn_sched_barrier(0);
    read_bf4<EP>(bf1, cur + H_B1 * 8192, bBase, s0, s1);
    stage_half(Bn + (long)n0 * ldb, ldb, nxt + H_B0 * 8192, w, l);
    asm volatile("s_waitcnt lgkmcnt(0)" ::: "memory");
    __builtin_amdgcn_sched_barrier(0);
    __builtin_amdgcn_s_setprio(1);
    do_mfma16<0, 1>(acc, af, bf1);
    __builtin_amdgcn_s_setprio(0);

    // ---- phase 2(+3): needs A1 of tile t ----
    asm volatile("s_waitcnt vmcnt(4)" ::: "memory");
    __builtin_amdgcn_s_barrier();
    __builtin_amdgcn_sched_barrier(0);
    read_af8<EP>(af, cur + H_A1 * 8192, aBase, s0, s1);
    stage_half(Bn + (long)(n0 + 128) * ldb, ldb, nxt + H_B1 * 8192, w, l);
    stage_half(An + (long)(m0 + 128) * lda, lda, nxt + H_A1 * 8192, w, l);
    asm volatile("s_waitcnt lgkmcnt(0)" ::: "memory");
    __builtin_amdgcn_sched_barrier(0);
    __builtin_amdgcn_s_setprio(1);
    do_mfma16<1, 0>(acc, af, bf0);
    do_mfma16<1, 1>(acc, af, bf1);
    __builtin_amdgcn_s_setprio(0);
  }
  asm volatile("s_waitcnt vmcnt(0)" ::: "memory");  // drain wrap-stage loads

  // epilogue. C/D mapping: col=lane&15, row=(lane>>4)*4+reg
  const int rb = m0 + wm * 64 + ((l >> 4) << 2);
  const int cb = n0 + wn * 32 + (l & 15);
#pragma unroll
  for (int mi = 0; mi < 8; ++mi) {
    const int row = rb + (mi >> 2) * 128 + (mi & 3) * 16;
#pragma unroll
    for (int ni = 0; ni < 4; ++ni) {
      const int col = cb + (ni >> 1) * 128 + (ni & 1) * 16;
#pragma unroll
      for (int j = 0; j < 4; ++j) {
        const float v = acc[mi][ni][j];
        if (EP == G8_GELU) {
          const float tt = v + bias[col];
          const float g = 0.5f * tt * (1.0f + erff(tt * 0.70710678118654752f));
          ((u16*)Cv)[(long)(row + j) * ldc + col] = f2bf(g);
        } else {  // G8_F32 (split-K partial)
          ((float*)Cv)[(long)z * sCz + (long)(row + j) * ldc + col] = v;
        }
      }
    }
  }
}

// out = p0 + p1 + b2 + fa  (f32x4 elementwise over [8192][512])
__global__ void combine_kernel(const float* __restrict__ p,
                               const float* __restrict__ fa,
                               const float* __restrict__ b2,
                               float* __restrict__ out) {
  const long i = (long)blockIdx.x * 256 + threadIdx.x;  // f32x4 index
  const f32x4 a = ((const f32x4*)p)[i];
  const f32x4 b = ((const f32x4*)(p + 8192L * 512))[i];
  const f32x4 f = ((const f32x4*)fa)[i];
  const f32x4 bb = ((const f32x4*)b2)[i & 127];
  ((f32x4*)out)[i] = a + b + f + bb;
}

// ---------------------------------------------------------------------------
// legacy 128x128 GEMM (m97 structure) for the small attention GEMMs
// ---------------------------------------------------------------------------
enum { EP_BF16 = 0, EP_PV = 1, EP_F32B = 2 };

template <int EP>
__launch_bounds__(256, 2)
__global__ void gemm_bt(const u16* __restrict__ A, int lda, long sAz,
                        const u16* __restrict__ Bt, int ldb, long sBz,
                        void* __restrict__ Cv, int ldc, long sCz,
                        int K, const float* __restrict__ bias,
                        const float* __restrict__ aux) {
  __shared__ u16 lA[128 * 32];
  __shared__ u16 lB[128 * 32];
  const int z = blockIdx.z;
  const u16* Ab = A + (long)z * sAz;
  const u16* Bb = Bt + (long)z * sBz;
  const int m0 = blockIdx.x * 128;
  const int n0 = blockIdx.y * 128;
  const int tid = threadIdx.x;
  const int w = tid >> 6;
  const int l = tid & 63;
  const int wr = w >> 1;
  const int wc = w & 1;

  f32x4 acc[4][4];
#pragma unroll
  for (int i = 0; i < 4; ++i)
#pragma unroll
    for (int j = 0; j < 4; ++j) acc[i][j] = (f32x4){0.f, 0.f, 0.f, 0.f};

  const int sm = w * 32 + (l >> 2);
  const int sk = (l & 3) * 8;
  const u16* ga0 = Ab + (long)(m0 + sm) * lda + sk;
  const u16* ga1 = Ab + (long)(m0 + sm + 16) * lda + sk;
  const u16* gb0 = Bb + (long)(n0 + sm) * ldb + sk;
  const u16* gb1 = Bb + (long)(n0 + sm + 16) * ldb + sk;
  u16* dA = &lA[w * 1024];
  u16* dB = &lB[w * 1024];

  const int aoff = (wr * 64 + (l & 15)) * 32 + (l >> 4) * 8;
  const int boff = (wc * 64 + (l & 15)) * 32 + (l >> 4) * 8;

  for (int k0 = 0; k0 < K; k0 += 32) {
    gload_lds16(ga0 + k0, dA);
    gload_lds16(ga1 + k0, dA + 512);
    gload_lds16(gb0 + k0, dB);
    gload_lds16(gb1 + k0, dB + 512);
    __syncthreads();
    short8 af[4], bfv[4];
#pragma unroll
    for (int mi = 0; mi < 4; ++mi)
      af[mi] = *(const short8*)&lA[aoff + mi * 16 * 32];
#pragma unroll
    for (int ni = 0; ni < 4; ++ni)
      bfv[ni] = *(const short8*)&lB[boff + ni * 16 * 32];
#pragma unroll
    for (int mi = 0; mi < 4; ++mi)
#pragma unroll
      for (int ni = 0; ni < 4; ++ni)
        acc[mi][ni] = MFMA16x16(af[mi], bfv[ni], acc[mi][ni]);
    __syncthreads();
  }

  const int rbase = m0 + wr * 64 + (l >> 4) * 4;
  const int cbase = n0 + wc * 64 + (l & 15);
#pragma unroll
  for (int mi = 0; mi < 4; ++mi) {
#pragma unroll
    for (int ni = 0; ni < 4; ++ni) {
#pragma unroll
      for (int j = 0; j < 4; ++j) {
        const int row = rbase + mi * 16 + j;
        const int col = cbase + ni * 16;
        const float v = acc[mi][ni][j];
        if (EP == EP_BF16) {
          ((u16*)Cv)[(long)z * sCz + (long)row * ldc + col] = f2bf(v);
        } else if (EP == EP_PV) {
          if (col < 42) {
            const float iv = aux[z * 1024 + row];
            ((u16*)Cv)[(long)row * ldc + z * 42 + col] = f2bf(v * iv);
          }
        } else {  // EP_F32B
          ((float*)Cv)[(long)row * ldc + col] = v + bias[col];
        }
      }
    }
  }
}

// ---------------------------------------------------------------------------
// LayerNorm / softmax / prep kernels
// ---------------------------------------------------------------------------
__global__ void ln1_kernel(const float* __restrict__ x,
                           const float* __restrict__ gamma,
                           const float* __restrict__ beta,
                           u16* __restrict__ n1) {
  __shared__ float red[16];
  const int s = blockIdx.x;
  const int t = threadIdx.x;
  const float* row = x + (long)s * 512;
  const float v0 = row[t];
  const float v1 = row[t + 256];
  float sum = wred_sum(v0 + v1);
  float sq = wred_sum(v0 * v0 + v1 * v1);
  if ((t & 63) == 0) { red[t >> 6] = sum; red[8 + (t >> 6)] = sq; }
  __syncthreads();
  sum = red[0] + red[1] + red[2] + red[3];
  sq = red[8] + red[9] + red[10] + red[11];
  const float mu = sum * (1.0f / 512.0f);
  const float rstd = rsqrtf(sq * (1.0f / 512.0f) - mu * mu + 1e-5f);
  n1[(long)s * 512 + t] = f2bf((v0 - mu) * rstd * gamma[t] + beta[t]);
  n1[(long)s * 512 + t + 256] =
      f2bf((v1 - mu) * rstd * gamma[t + 256] + beta[t + 256]);
}

__global__ void ln2_kernel(const float* __restrict__ x,
                           const float* __restrict__ aproj,
                           const float* __restrict__ gamma,
                           const float* __restrict__ beta,
                           float* __restrict__ fa, u16* __restrict__ n2) {
  __shared__ float red[16];
  const int r = blockIdx.x;
  const int t = threadIdx.x;
  const int s = r & 1023;
  const float* xr = x + (long)r * 512;
  const float* ar = aproj + (long)s * 512;
  const float v0 = xr[t] + ar[t];
  const float v1 = xr[t + 256] + ar[t + 256];
  fa[(long)r * 512 + t] = v0;
  fa[(long)r * 512 + t + 256] = v1;
  float sum = wred_sum(v0 + v1);
  float sq = wred_sum(v0 * v0 + v1 * v1);
  if ((t & 63) == 0) { red[t >> 6] = sum; red[8 + (t >> 6)] = sq; }
  __syncthreads();
  sum = red[0] + red[1] + red[2] + red[3];
  sq = red[8] + red[9] + red[10] + red[11];
  const float mu = sum * (1.0f / 512.0f);
  const float rstd = rsqrtf(sq * (1.0f / 512.0f) - mu * mu + 1e-5f);
  n2[(long)r * 512 + t] = f2bf((v0 - mu) * rstd * gamma[t] + beta[t]);
  n2[(long)r * 512 + t + 256] =
      f2bf((v1 - mu) * rstd * gamma[t + 256] + beta[t + 256]);
}

__global__ void softmax_kernel(u16* __restrict__ SP, float* __restrict__ invl) {
  __shared__ float red[16];
  const long row = blockIdx.x;
  u16* p = SP + row * 1024;
  const int t = threadIdx.x;
  uint2 u = ((const uint2*)p)[t];
  const float s0 = bf2f((u16)(u.x & 0xffff));
  const float s1 = bf2f((u16)(u.x >> 16));
  const float s2 = bf2f((u16)(u.y & 0xffff));
  const float s3 = bf2f((u16)(u.y >> 16));
  float m = wred_max(fmaxf(fmaxf(s0, s1), fmaxf(s2, s3)));
  if ((t & 63) == 0) red[t >> 6] = m;
  __syncthreads();
  m = fmaxf(fmaxf(red[0], red[1]), fmaxf(red[2], red[3]));
  const float e0 = __expf(s0 - m), e1 = __expf(s1 - m);
  const float e2 = __expf(s2 - m), e3 = __expf(s3 - m);
  float sum = wred_sum(e0 + e1 + e2 + e3);
  if ((t & 63) == 0) red[8 + (t >> 6)] = sum;
  __syncthreads();
  sum = red[8] + red[9] + red[10] + red[11];
  if (t == 0) invl[row] = 1.0f / sum;
  uint2 o;
  o.x = (unsigned)f2bf(e0) | ((unsigned)f2bf(e1) << 16);
  o.y = (unsigned)f2bf(e2) | ((unsigned)f2bf(e3) << 16);
  ((uint2*)p)[t] = o;
}

__global__ void prep_qkv_kernel(const float* __restrict__ wq,
                                const float* __restrict__ wk,
                                u16* __restrict__ BtQKV, float scale) {
  const int i = blockIdx.x * 256 + threadIdx.x;
  const int n = i >> 9, d = i & 511;
  const int pq = n / 768;
  const int h = (n % 768) >> 6;
  const int e = n & 63;
  float v = 0.f;
  if (e < 42) {
    v = (pq ? wk : wq)[((long)h * 512 + d) * 42 + e];
    if (!pq) v *= scale;
  }
  BtQKV[i] = f2bf(v);
}
__global__ void prep_wvT_kernel(const float* __restrict__ wv,
                                u16* __restrict__ wvT) {
  const int i = blockIdx.x * 256 + threadIdx.x;
  const int r = i >> 9, d = i & 511;
  const int h = r >> 7, e = r & 127;
  wvT[i] = f2bf(e < 42 ? wv[((long)h * 512 + d) * 42 + e] : 0.f);
}
__global__ void prep_proj_kernel(const float* __restrict__ wp,
                                 u16* __restrict__ BtP) {
  const int i = blockIdx.x * 256 + threadIdx.x;
  const int n = i >> 9, k = i & 511;
  BtP[i] = f2bf(k < 504 ? wp[(long)k * 512 + n] : 0.f);
}
__global__ void prep_w1_kernel(const float* __restrict__ w1,
                               u16* __restrict__ Bt1) {
  const int i = blockIdx.x * 256 + threadIdx.x;  // [2048][512]
  const int n = i >> 9, k = i & 511;
  Bt1[i] = f2bf(w1[(long)k * 2048 + n]);
}
__global__ void prep_w2_kernel(const float* __restrict__ w2,
                               u16* __restrict__ Bt2) {
  const int i = blockIdx.x * 256 + threadIdx.x;  // [512][2048]
  const int n = i >> 11, k = i & 2047;
  Bt2[i] = f2bf(w2[(long)k * 512 + n]);
}
__global__ void zero_u16_kernel(u16* __restrict__ p) {
  p[blockIdx.x * 256 + threadIdx.x] = 0;
}

// ---------------------------------------------------------------------------
extern "C" void kernel_launch(void* const* d_in, const int* in_sizes, int n_in,
                              void* d_out, int out_size, void* d_ws,
                              size_t ws_size, hipStream_t stream) {
  const float* x = (const float*)d_in[0];
  const float* wk = (const float*)d_in[1];
  const float* wq = (const float*)d_in[2];
  const float* wv = (const float*)d_in[3];
  const float* w_proj = (const float*)d_in[4];
  const float* b_proj = (const float*)d_in[5];
  const float* gamma = (const float*)d_in[6];
  const float* beta = (const float*)d_in[7];
  const float* w1 = (const float*)d_in[8];
  const float* b1 = (const float*)d_in[9];
  const float* w2 = (const float*)d_in[10];
  const float* b2 = (const float*)d_in[11];

  char* base = (char*)d_ws;
  size_t off = 0;
  auto alloc = [&](size_t bytes) -> void* {
    void* p = base + off;
    off += (bytes + 255) & ~(size_t)255;
    return p;
  };
  // [n1..aproj) spans the first ~37 MB and is dead by MLP2 time -> the
  // split-K partial buffer (33.6 MB) aliases offset 0.
  u16* n1 = (u16*)alloc(1024L * 512 * 2);
  u16* qkvc = (u16*)alloc(1024L * 1536 * 2);
  u16* SP = (u16*)alloc(12L * 1024 * 1024 * 2);
  u16* wvT = (u16*)alloc(1536L * 512 * 2);
  u16* vt = (u16*)alloc(1536L * 1024 * 2);
  u16* cat = (u16*)alloc(1024L * 512 * 2);
  float* aproj = (float*)alloc(1024L * 512 * 4);
  float* fa = (float*)alloc(8192L * 512 * 4);
  u16* n2 = (u16*)alloc(8192L * 512 * 2);
  u16* hbuf = (u16*)alloc(8192L * 2048 * 2);
  u16* BtQKV = (u16*)alloc(1536L * 512 * 2);
  u16* BtP = (u16*)alloc(512L * 512 * 2);
  u16* Bt1 = (u16*)alloc(2048L * 512 * 2);
  u16* Bt2 = (u16*)alloc(512L * 2048 * 2);
  float* invl = (float*)alloc(12L * 1024 * 4);
  float* part = (float*)d_ws;  // aliases n1..aproj (dead by MLP2)
  (void)ws_size; (void)in_sizes; (void)n_in; (void)out_size;

  const float scale = 0.15430334996209191f;  // 42^-0.5 folded into q weights

  prep_qkv_kernel<<<3072, 256, 0, stream>>>(wq, wk, BtQKV, scale);
  prep_wvT_kernel<<<3072, 256, 0, stream>>>(wv, wvT);
  prep_proj_kernel<<<1024, 256, 0, stream>>>(w_proj, BtP);
  prep_w1_kernel<<<4096, 256, 0, stream>>>(w1, Bt1);
  prep_w2_kernel<<<4096, 256, 0, stream>>>(w2, Bt2);
  zero_u16_kernel<<<2048, 256, 0, stream>>>(cat);
  ln1_kernel<<<1024, 256, 0, stream>>>(x, gamma, beta, n1);

  // q,k = n1 @ {wq*scale, wk}: [1024,1536], K=512
  gemm_bt<EP_BF16><<<dim3(8, 12, 1), 256, 0, stream>>>(
      n1, 512, 0, BtQKV, 512, 0, qkvc, 1536, 0, 512, nullptr, nullptr);
  // vt = wvT @ n1^T: [1536,1024], K=512
  gemm_bt<EP_BF16><<<dim3(12, 8, 1), 256, 0, stream>>>(
      wvT, 512, 0, n1, 512, 0, vt, 1024, 0, 512, nullptr, nullptr);
  // scores per head: q_h [1024,64] x k_h^T -> [1024,1024] bf16
  gemm_bt<EP_BF16><<<dim3(8, 8, 12), 256, 0, stream>>>(
      qkvc, 1536, 64, qkvc + 768, 1536, 64, SP, 1024, 1024L * 1024, 64,
      nullptr, nullptr);
  softmax_kernel<<<12288, 256, 0, stream>>>(SP, invl);
  // out_h = P_h @ v_h: keep cols<42, /l, scatter into concat
  gemm_bt<EP_PV><<<dim3(8, 1, 12), 256, 0, stream>>>(
      SP, 1024, 1024L * 1024, vt, 1024, 128L * 1024, cat, 512, 0, 1024,
      nullptr, invl);
  // attn_proj = concat @ w_proj + b_proj: [1024,512] f32
  gemm_bt<EP_F32B><<<dim3(8, 4, 1), 256, 0, stream>>>(
      cat, 512, 0, BtP, 512, 0, aproj, 512, 0, 512, b_proj, nullptr);
  ln2_kernel<<<8192, 256, 0, stream>>>(x, aproj, gamma, beta, fa, n2);
  // h = gelu(n2 @ w1 + b1): [8192,2048] bf16  (8-phase 256^2 kernel)
  gemm8<G8_GELU><<<dim3(32, 8, 1), 512, 0, stream>>>(
      n2, 512, 0, Bt1, 512, 0, hbuf, 2048, 0, 512, b1);
  // out partials = h @ w2 (split-K=2): z strides K by 1024
  gemm8<G8_F32><<<dim3(32, 2, 2), 512, 0, stream>>>(
      hbuf, 2048, 1024, Bt2, 2048, 1024, part, 512, 8192L * 512, 1024,
      nullptr);
  // out = p0 + p1 + b2 + fa
  combine_kernel<<<4096, 256, 0, stream>>>(part, fa, b2, (float*)d_out);
}

// Round 3
// 188.312 us; speedup vs baseline: 1.1466x; 1.1466x over previous
//
#include <hip/hip_runtime.h>
#include <hip/hip_bf16.h>
#include <stdint.h>

// EncoderBlock: B=8, S=1024, D=512, H=12, HS=42 (padded to 64 for GEMM).
// Only batch 0's attention is used (reference quirk: attn[0] + x).

typedef unsigned short u16;
typedef __attribute__((ext_vector_type(8))) short short8;  // 8 bf16 = 4 VGPRs
typedef __attribute__((ext_vector_type(4))) float f32x4;

__device__ __forceinline__ u16 f2bf(float f) {
  union { float f; unsigned u; } x; x.f = f;
  return (u16)((x.u + 0x7FFFu + ((x.u >> 16) & 1u)) >> 16);  // RNE
}
__device__ __forceinline__ float bf2f(u16 u) {
  union { unsigned u; float f; } x; x.u = ((unsigned)u) << 16;
  return x.f;
}

// async global->LDS, 16B per lane; LDS dest is wave-uniform base + lane*16.
__device__ __forceinline__ void gload_lds16(const u16* g, u16* l) {
  __builtin_amdgcn_global_load_lds(
      (__attribute__((address_space(1))) void*)g,
      (__attribute__((address_space(3))) void*)l, 16, 0, 0);
}

__device__ __forceinline__ float wred_sum(float v) {
#pragma unroll
  for (int off = 32; off > 0; off >>= 1) v += __shfl_xor(v, off, 64);
  return v;
}
__device__ __forceinline__ float wred_max(float v) {
#pragma unroll
  for (int off = 32; off > 0; off >>= 1) v = fmaxf(v, __shfl_xor(v, off, 64));
  return v;
}

#define MFMA16x16(a, b, c) __builtin_amdgcn_mfma_f32_16x16x32_bf16(a, b, c, 0, 0, 0)

// ---------------------------------------------------------------------------
// GEMM: C[m][n] = sum_k A[m][k] * Bt[n][k]   (A,Bt bf16 row-major; Bt is B^T)
// 128x128 tile, BK=32, 4 waves (2x2), mfma_f32_16x16x32_bf16.
// Double-buffered LDS (32 KB total -> 4 blocks/CU), ONE barrier per K-tile:
//   loop: { ds_read frags from buf; stage(t+1 -> buf^1); MFMA; __syncthreads }
// All reads of buf complete before the barrier; all writes target buf^1, so a
// single sync (vmcnt(0)+lgkmcnt(0)+s_barrier) per tile is sufficient. Next-tile
// global loads fly under the MFMA cluster + barrier drain (T3 minimum-2-phase,
// m228d/m248-proven structure; no inline asm, compiler-managed waits).
// Epilogues: 0=bf16 store, 1=PV (col<42, *invl, scatter to concat),
//            2=f32+bias, 3=gelu(x+bias)->bf16, 4=f32+bias+resid (final out)
// ---------------------------------------------------------------------------
enum { EP_BF16 = 0, EP_PV = 1, EP_F32B = 2, EP_GELU = 3, EP_OUT = 4 };

template <int EP>
__launch_bounds__(256, 4)
__global__ void gemm2(const u16* __restrict__ A, int lda, long sAz,
                      const u16* __restrict__ Bt, int ldb, long sBz,
                      void* __restrict__ Cv, int ldc, long sCz,
                      int K, const float* __restrict__ bias,
                      const float* __restrict__ aux) {
  __shared__ u16 lA[2][128 * 32];  // [buf][m][k] linear, 8KB each
  __shared__ u16 lB[2][128 * 32];  // [buf][n][k] linear
  const int z = blockIdx.z;
  const u16* Ab = A + (long)z * sAz;
  const u16* Bb = Bt + (long)z * sBz;
  const int m0 = blockIdx.x * 128;
  const int n0 = blockIdx.y * 128;
  const int tid = threadIdx.x;
  const int w = tid >> 6;
  const int l = tid & 63;
  const int wr = w >> 1;
  const int wc = w & 1;
  const int NT = K >> 5;

  f32x4 acc[4][4];
#pragma unroll
  for (int i = 0; i < 4; ++i)
#pragma unroll
    for (int j = 0; j < 4; ++j) acc[i][j] = (f32x4){0.f, 0.f, 0.f, 0.f};

  // staging: wave w covers tile rows [w*32, w*32+32), 2 instrs of 1KB each
  // per matrix. lane -> (row = l>>2, k-granule = l&3); 1KB = 16 rows x 64B.
  const int srow = w * 32 + (l >> 2);
  const int sk = (l & 3) * 8;
  const u16* ga0 = Ab + (long)(m0 + srow) * lda + sk;
  const u16* ga1 = Ab + (long)(m0 + srow + 16) * lda + sk;
  const u16* gb0 = Bb + (long)(n0 + srow) * ldb + sk;
  const u16* gb1 = Bb + (long)(n0 + srow + 16) * ldb + sk;
  const int dOff = w * 1024;  // u16 elements: 16 rows * 32 k * (w)

  // fragment read offsets: row = wr*64 + (l&15), k-granule = l>>4
  const int aoff = (wr * 64 + (l & 15)) * 32 + (l >> 4) * 8;
  const int boff = (wc * 64 + (l & 15)) * 32 + (l >> 4) * 8;

  // prologue: stage tile 0 into buf 0
  gload_lds16(ga0, &lA[0][dOff]);
  gload_lds16(ga1, &lA[0][dOff + 512]);
  gload_lds16(gb0, &lB[0][dOff]);
  gload_lds16(gb1, &lB[0][dOff + 512]);
  __syncthreads();

  int buf = 0;
  for (int t = 0; t < NT; ++t) {
    short8 af[4], bfv[4];
#pragma unroll
    for (int mi = 0; mi < 4; ++mi)
      af[mi] = *(const short8*)&lA[buf][aoff + mi * 16 * 32];
#pragma unroll
    for (int ni = 0; ni < 4; ++ni)
      bfv[ni] = *(const short8*)&lB[buf][boff + ni * 16 * 32];
    if (t + 1 < NT) {
      const int k0 = (t + 1) * 32;
      const int nb = buf ^ 1;
      gload_lds16(ga0 + k0, &lA[nb][dOff]);
      gload_lds16(ga1 + k0, &lA[nb][dOff + 512]);
      gload_lds16(gb0 + k0, &lB[nb][dOff]);
      gload_lds16(gb1 + k0, &lB[nb][dOff + 512]);
    }
#pragma unroll
    for (int mi = 0; mi < 4; ++mi)
#pragma unroll
      for (int ni = 0; ni < 4; ++ni)
        acc[mi][ni] = MFMA16x16(af[mi], bfv[ni], acc[mi][ni]);
    __syncthreads();
    buf ^= 1;
  }

  // C/D mapping: col = lane&15, row = (lane>>4)*4 + reg  [m89-verified]
  const int rbase = m0 + wr * 64 + (l >> 4) * 4;
  const int cbase = n0 + wc * 64 + (l & 15);
#pragma unroll
  for (int mi = 0; mi < 4; ++mi) {
#pragma unroll
    for (int ni = 0; ni < 4; ++ni) {
#pragma unroll
      for (int j = 0; j < 4; ++j) {
        const int row = rbase + mi * 16 + j;
        const int col = cbase + ni * 16;
        const float v = acc[mi][ni][j];
        if (EP == EP_BF16) {
          ((u16*)Cv)[(long)z * sCz + (long)row * ldc + col] = f2bf(v);
        } else if (EP == EP_PV) {
          if (col < 42) {  // n0 == 0 here; col is within-head dim
            const float iv = aux[z * 1024 + row];
            ((u16*)Cv)[(long)row * ldc + z * 42 + col] = f2bf(v * iv);
          }
        } else if (EP == EP_F32B) {
          ((float*)Cv)[(long)row * ldc + col] = v + bias[col];
        } else if (EP == EP_GELU) {
          const float tt = v + bias[col];
          const float g = 0.5f * tt * (1.0f + erff(tt * 0.70710678118654752f));
          ((u16*)Cv)[(long)row * ldc + col] = f2bf(g);
        } else {  // EP_OUT
          ((float*)Cv)[(long)row * ldc + col] =
              v + bias[col] + aux[(long)row * ldc + col];
        }
      }
    }
  }
}

// ---------------------------------------------------------------------------
// LayerNorm / softmax / prep kernels
// ---------------------------------------------------------------------------
__global__ void ln1_kernel(const float* __restrict__ x,
                           const float* __restrict__ gamma,
                           const float* __restrict__ beta,
                           u16* __restrict__ n1) {
  __shared__ float red[16];
  const int s = blockIdx.x;
  const int t = threadIdx.x;
  const float* row = x + (long)s * 512;
  const float v0 = row[t];
  const float v1 = row[t + 256];
  float sum = wred_sum(v0 + v1);
  float sq = wred_sum(v0 * v0 + v1 * v1);
  if ((t & 63) == 0) { red[t >> 6] = sum; red[8 + (t >> 6)] = sq; }
  __syncthreads();
  sum = red[0] + red[1] + red[2] + red[3];
  sq = red[8] + red[9] + red[10] + red[11];
  const float mu = sum * (1.0f / 512.0f);
  const float rstd = rsqrtf(sq * (1.0f / 512.0f) - mu * mu + 1e-5f);
  n1[(long)s * 512 + t] = f2bf((v0 - mu) * rstd * gamma[t] + beta[t]);
  n1[(long)s * 512 + t + 256] =
      f2bf((v1 - mu) * rstd * gamma[t + 256] + beta[t + 256]);
}

__global__ void ln2_kernel(const float* __restrict__ x,
                           const float* __restrict__ aproj,
                           const float* __restrict__ gamma,
                           const float* __restrict__ beta,
                           float* __restrict__ fa, u16* __restrict__ n2) {
  __shared__ float red[16];
  const int r = blockIdx.x;  // b*1024 + s
  const int t = threadIdx.x;
  const int s = r & 1023;
  const float* xr = x + (long)r * 512;
  const float* ar = aproj + (long)s * 512;
  const float v0 = xr[t] + ar[t];
  const float v1 = xr[t + 256] + ar[t + 256];
  fa[(long)r * 512 + t] = v0;
  fa[(long)r * 512 + t + 256] = v1;
  float sum = wred_sum(v0 + v1);
  float sq = wred_sum(v0 * v0 + v1 * v1);
  if ((t & 63) == 0) { red[t >> 6] = sum; red[8 + (t >> 6)] = sq; }
  __syncthreads();
  sum = red[0] + red[1] + red[2] + red[3];
  sq = red[8] + red[9] + red[10] + red[11];
  const float mu = sum * (1.0f / 512.0f);
  const float rstd = rsqrtf(sq * (1.0f / 512.0f) - mu * mu + 1e-5f);
  n2[(long)r * 512 + t] = f2bf((v0 - mu) * rstd * gamma[t] + beta[t]);
  n2[(long)r * 512 + t + 256] =
      f2bf((v1 - mu) * rstd * gamma[t + 256] + beta[t + 256]);
}

// in-place row softmax over bf16 scores [12*1024][1024]; stores 1/sum
__global__ void softmax_kernel(u16* __restrict__ SP, float* __restrict__ invl) {
  __shared__ float red[16];
  const long row = blockIdx.x;
  u16* p = SP + row * 1024;
  const int t = threadIdx.x;
  uint2 u = ((const uint2*)p)[t];
  const float s0 = bf2f((u16)(u.x & 0xffff));
  const float s1 = bf2f((u16)(u.x >> 16));
  const float s2 = bf2f((u16)(u.y & 0xffff));
  const float s3 = bf2f((u16)(u.y >> 16));
  float m = wred_max(fmaxf(fmaxf(s0, s1), fmaxf(s2, s3)));
  if ((t & 63) == 0) red[t >> 6] = m;
  __syncthreads();
  m = fmaxf(fmaxf(red[0], red[1]), fmaxf(red[2], red[3]));
  const float e0 = __expf(s0 - m), e1 = __expf(s1 - m);
  const float e2 = __expf(s2 - m), e3 = __expf(s3 - m);
  float sum = wred_sum(e0 + e1 + e2 + e3);
  if ((t & 63) == 0) red[8 + (t >> 6)] = sum;
  __syncthreads();
  sum = red[8] + red[9] + red[10] + red[11];
  if (t == 0) invl[row] = 1.0f / sum;
  uint2 o;
  o.x = (unsigned)f2bf(e0) | ((unsigned)f2bf(e1) << 16);
  o.y = (unsigned)f2bf(e2) | ((unsigned)f2bf(e3) << 16);
  ((uint2*)p)[t] = o;
}

__global__ void prep_qkv_kernel(const float* __restrict__ wq,
                                const float* __restrict__ wk,
                                u16* __restrict__ BtQKV, float scale) {
  const int i = blockIdx.x * 256 + threadIdx.x;
  const int n = i >> 9, d = i & 511;
  const int pq = n / 768;
  const int h = (n % 768) >> 6;
  const int e = n & 63;
  float v = 0.f;
  if (e < 42) {
    v = (pq ? wk : wq)[((long)h * 512 + d) * 42 + e];
    if (!pq) v *= scale;
  }
  BtQKV[i] = f2bf(v);
}
__global__ void prep_wvT_kernel(const float* __restrict__ wv,
                                u16* __restrict__ wvT) {
  const int i = blockIdx.x * 256 + threadIdx.x;
  const int r = i >> 9, d = i & 511;
  const int h = r >> 7, e = r & 127;
  wvT[i] = f2bf(e < 42 ? wv[((long)h * 512 + d) * 42 + e] : 0.f);
}
__global__ void prep_proj_kernel(const float* __restrict__ wp,
                                 u16* __restrict__ BtP) {
  const int i = blockIdx.x * 256 + threadIdx.x;
  const int n = i >> 9, k = i & 511;
  BtP[i] = f2bf(k < 504 ? wp[(long)k * 512 + n] : 0.f);
}
__global__ void prep_w1_kernel(const float* __restrict__ w1,
                               u16* __restrict__ Bt1) {
  const int i = blockIdx.x * 256 + threadIdx.x;  // [2048][512]
  const int n = i >> 9, k = i & 511;
  Bt1[i] = f2bf(w1[(long)k * 2048 + n]);
}
__global__ void prep_w2_kernel(const float* __restrict__ w2,
                               u16* __restrict__ Bt2) {
  const int i = blockIdx.x * 256 + threadIdx.x;  // [512][2048]
  const int n = i >> 11, k = i & 2047;
  Bt2[i] = f2bf(w2[(long)k * 512 + n]);
}
__global__ void zero_u16_kernel(u16* __restrict__ p) {
  p[blockIdx.x * 256 + threadIdx.x] = 0;
}

// ---------------------------------------------------------------------------
extern "C" void kernel_launch(void* const* d_in, const int* in_sizes, int n_in,
                              void* d_out, int out_size, void* d_ws,
                              size_t ws_size, hipStream_t stream) {
  const float* x = (const float*)d_in[0];
  const float* wk = (const float*)d_in[1];   // wk before wq in dict order
  const float* wq = (const float*)d_in[2];
  const float* wv = (const float*)d_in[3];
  const float* w_proj = (const float*)d_in[4];
  const float* b_proj = (const float*)d_in[5];
  const float* gamma = (const float*)d_in[6];
  const float* beta = (const float*)d_in[7];
  const float* w1 = (const float*)d_in[8];
  const float* b1 = (const float*)d_in[9];
  const float* w2 = (const float*)d_in[10];
  const float* b2 = (const float*)d_in[11];

  char* base = (char*)d_ws;
  size_t off = 0;
  auto alloc = [&](size_t bytes) -> void* {
    void* p = base + off;
    off += (bytes + 255) & ~(size_t)255;
    return p;
  };
  u16* n1 = (u16*)alloc(1024L * 512 * 2);        // LN1(x[0]) bf16
  u16* qkvc = (u16*)alloc(1024L * 1536 * 2);     // [s][(q|k) h e64] bf16
  u16* SP = (u16*)alloc(12L * 1024 * 1024 * 2);  // scores -> P, bf16, in-place
  u16* wvT = (u16*)alloc(1536L * 512 * 2);       // [h*128+e][d]
  u16* vt = (u16*)alloc(1536L * 1024 * 2);       // v^T [h*128+e][t]
  u16* cat = (u16*)alloc(1024L * 512 * 2);       // concat heads, pad 504->512
  float* aproj = (float*)alloc(1024L * 512 * 4); // attn @ w_proj + b_proj
  float* fa = (float*)alloc(8192L * 512 * 4);    // first_added, f32
  u16* n2 = (u16*)alloc(8192L * 512 * 2);        // LN2 bf16
  u16* hbuf = (u16*)alloc(8192L * 2048 * 2);     // gelu(mlp1) bf16
  u16* BtQKV = (u16*)alloc(1536L * 512 * 2);
  u16* BtP = (u16*)alloc(512L * 512 * 2);
  u16* Bt1 = (u16*)alloc(2048L * 512 * 2);
  u16* Bt2 = (u16*)alloc(512L * 2048 * 2);
  float* invl = (float*)alloc(12L * 1024 * 4);
  (void)ws_size; (void)in_sizes; (void)n_in; (void)out_size;

  const float scale = 0.15430334996209191f;  // 42^-0.5 folded into q weights

  prep_qkv_kernel<<<3072, 256, 0, stream>>>(wq, wk, BtQKV, scale);
  prep_wvT_kernel<<<3072, 256, 0, stream>>>(wv, wvT);
  prep_proj_kernel<<<1024, 256, 0, stream>>>(w_proj, BtP);
  prep_w1_kernel<<<4096, 256, 0, stream>>>(w1, Bt1);
  prep_w2_kernel<<<4096, 256, 0, stream>>>(w2, Bt2);
  zero_u16_kernel<<<2048, 256, 0, stream>>>(cat);
  ln1_kernel<<<1024, 256, 0, stream>>>(x, gamma, beta, n1);

  // q,k = n1 @ {wq*scale, wk}: [1024,1536], K=512
  gemm2<EP_BF16><<<dim3(8, 12, 1), 256, 0, stream>>>(
      n1, 512, 0, BtQKV, 512, 0, qkvc, 1536, 0, 512, nullptr, nullptr);
  // vt = wvT @ n1^T: [1536,1024], K=512
  gemm2<EP_BF16><<<dim3(12, 8, 1), 256, 0, stream>>>(
      wvT, 512, 0, n1, 512, 0, vt, 1024, 0, 512, nullptr, nullptr);
  // scores per head: q_h [1024,64] x k_h^T -> [1024,1024] bf16
  gemm2<EP_BF16><<<dim3(8, 8, 12), 256, 0, stream>>>(
      qkvc, 1536, 64, qkvc + 768, 1536, 64, SP, 1024, 1024L * 1024, 64,
      nullptr, nullptr);
  softmax_kernel<<<12288, 256, 0, stream>>>(SP, invl);
  // out_h = P_h @ v_h: keep cols<42, /l, scatter into concat
  gemm2<EP_PV><<<dim3(8, 1, 12), 256, 0, stream>>>(
      SP, 1024, 1024L * 1024, vt, 1024, 128L * 1024, cat, 512, 0, 1024,
      nullptr, invl);
  // attn_proj = concat @ w_proj + b_proj: [1024,512] f32
  gemm2<EP_F32B><<<dim3(8, 4, 1), 256, 0, stream>>>(
      cat, 512, 0, BtP, 512, 0, aproj, 512, 0, 512, b_proj, nullptr);
  ln2_kernel<<<8192, 256, 0, stream>>>(x, aproj, gamma, beta, fa, n2);
  // h = gelu(n2 @ w1 + b1): [8192,2048] bf16
  gemm2<EP_GELU><<<dim3(64, 16, 1), 256, 0, stream>>>(
      n2, 512, 0, Bt1, 512, 0, hbuf, 2048, 0, 512, b1, nullptr);
  // out = h @ w2 + b2 + fa: [8192,512] f32
  gemm2<EP_OUT><<<dim3(64, 4, 1), 256, 0, stream>>>(
      hbuf, 2048, 0, Bt2, 2048, 0, d_out, 512, 0, 2048, b2, fa);
}

// Round 4
// 185.104 us; speedup vs baseline: 1.1664x; 1.0173x over previous
//
#include <hip/hip_runtime.h>
#include <hip/hip_bf16.h>
#include <stdint.h>

// EncoderBlock: B=8, S=1024, D=512, H=12, HS=42 (padded to 64 for GEMM).
// Only batch 0's attention is used (reference quirk: attn[0] + x).

typedef unsigned short u16;
typedef __attribute__((ext_vector_type(8))) short short8;  // 8 bf16 = 4 VGPRs
typedef __attribute__((ext_vector_type(4))) float f32x4;

__device__ __forceinline__ u16 f2bf(float f) {
  union { float f; unsigned u; } x; x.f = f;
  return (u16)((x.u + 0x7FFFu + ((x.u >> 16) & 1u)) >> 16);  // RNE
}
__device__ __forceinline__ float bf2f(u16 u) {
  union { unsigned u; float f; } x; x.u = ((unsigned)u) << 16;
  return x.f;
}

// async global->LDS, 16B per lane; LDS dest is wave-uniform base + lane*16.
__device__ __forceinline__ void gload_lds16(const u16* g, u16* l) {
  __builtin_amdgcn_global_load_lds(
      (__attribute__((address_space(1))) void*)g,
      (__attribute__((address_space(3))) void*)l, 16, 0, 0);
}

__device__ __forceinline__ float wred_sum(float v) {
#pragma unroll
  for (int off = 32; off > 0; off >>= 1) v += __shfl_xor(v, off, 64);
  return v;
}
__device__ __forceinline__ float wred_max(float v) {
#pragma unroll
  for (int off = 32; off > 0; off >>= 1) v = fmaxf(v, __shfl_xor(v, off, 64));
  return v;
}

#define MFMA16x16(a, b, c) __builtin_amdgcn_mfma_f32_16x16x32_bf16(a, b, c, 0, 0, 0)

// ---------------------------------------------------------------------------
// GEMM: C[m][n] = sum_k A[m][k] * Bt[n][k]   (A,Bt bf16 row-major; Bt is B^T)
// 128x128 tile, BK=32, 4 waves (2x2), mfma_f32_16x16x32_bf16, dbuf LDS.
// LDS granule swizzle (bank-conflict fix): within each 64B row, 16B granule
//   g_phys = g_log ^ ((row>>1)&3).  Involution; applied on the STAGE SOURCE
//   column (LDS dest of global_load_lds stays linear, per m104) and on the
//   ds_read granule. Result: every aligned 8-lane group of a fragment read
//   covers all 8 bank-quads exactly once == contiguous pattern == conflict-
//   free (was 4-way: lanes 0-7 hit quads {0,4,0,4,...}, 2.1M conflicts).
// Epilogues: 0=bf16, 1=PV-scaled scatter, 2=f32+bias, 3=gelu->bf16,
//            4=f32+bias+resid, 5=f32 partial (split-K), 6=PV f32 partial.
// ---------------------------------------------------------------------------
enum { EP_BF16 = 0, EP_PV = 1, EP_F32B = 2, EP_GELU = 3, EP_OUT = 4,
       EP_PART = 5, EP_PVPART = 6 };

template <int EP>
__launch_bounds__(256, 4)
__global__ void gemm2(const u16* __restrict__ A, int lda, long sAz,
                      const u16* __restrict__ Bt, int ldb, long sBz,
                      void* __restrict__ Cv, int ldc, long sCz,
                      int K, const float* __restrict__ bias,
                      const float* __restrict__ aux) {
  __shared__ u16 lA[2][128 * 32];  // [buf][m][k-granule-swizzled], 8KB each
  __shared__ u16 lB[2][128 * 32];
  const int z = blockIdx.z;
  const u16* Ab;
  const u16* Bb;
  if (EP == EP_PVPART) {  // z = head*4 + kslice, kslice covers 256 of K
    Ab = A + (long)(z >> 2) * sAz + (z & 3) * 256;
    Bb = Bt + (long)(z >> 2) * sBz + (z & 3) * 256;
  } else {
    Ab = A + (long)z * sAz;
    Bb = Bt + (long)z * sBz;
  }
  const int m0 = blockIdx.x * 128;
  const int n0 = blockIdx.y * 128;
  const int tid = threadIdx.x;
  const int w = tid >> 6;
  const int l = tid & 63;
  const int wr = w >> 1;
  const int wc = w & 1;
  const int NT = K >> 5;

  f32x4 acc[4][4];
#pragma unroll
  for (int i = 0; i < 4; ++i)
#pragma unroll
    for (int j = 0; j < 4; ++j) acc[i][j] = (f32x4){0.f, 0.f, 0.f, 0.f};

  // staging: wave w covers tile rows [w*32, w*32+32), lane -> row l>>2,
  // granule l&3; SOURCE granule swizzled by ((row>>1)&3) = (l>>3)&3
  // (same for the +16-row load: +16 rows shifts row>>1 by 8 == 0 mod 4).
  const int srow = w * 32 + (l >> 2);
  const int sk = ((l & 3) ^ ((l >> 3) & 3)) * 8;
  const u16* ga0 = Ab + (long)(m0 + srow) * lda + sk;
  const u16* ga1 = Ab + (long)(m0 + srow + 16) * lda + sk;
  const u16* gb0 = Bb + (long)(n0 + srow) * ldb + sk;
  const u16* gb1 = Bb + (long)(n0 + srow + 16) * ldb + sk;
  const int dOff = w * 1024;

  // fragment reads: row = (l&15) (+16*mi, no effect on swizzle), logical
  // granule G = l>>4, physical = G ^ ((row>>1)&3) = (l>>4) ^ ((l>>1)&3)
  const int gphys = ((l >> 4) ^ ((l >> 1) & 3)) * 8;
  const int aoff = (wr * 64 + (l & 15)) * 32 + gphys;
  const int boff = (wc * 64 + (l & 15)) * 32 + gphys;

  // prologue: stage tile 0 into buf 0
  gload_lds16(ga0, &lA[0][dOff]);
  gload_lds16(ga1, &lA[0][dOff + 512]);
  gload_lds16(gb0, &lB[0][dOff]);
  gload_lds16(gb1, &lB[0][dOff + 512]);
  __syncthreads();

  int buf = 0;
  for (int t = 0; t < NT; ++t) {
    short8 af[4], bfv[4];
#pragma unroll
    for (int mi = 0; mi < 4; ++mi)
      af[mi] = *(const short8*)&lA[buf][aoff + mi * 16 * 32];
#pragma unroll
    for (int ni = 0; ni < 4; ++ni)
      bfv[ni] = *(const short8*)&lB[buf][boff + ni * 16 * 32];
    if (t + 1 < NT) {
      const int k0 = (t + 1) * 32;
      const int nb = buf ^ 1;
      gload_lds16(ga0 + k0, &lA[nb][dOff]);
      gload_lds16(ga1 + k0, &lA[nb][dOff + 512]);
      gload_lds16(gb0 + k0, &lB[nb][dOff]);
      gload_lds16(gb1 + k0, &lB[nb][dOff + 512]);
    }
#pragma unroll
    for (int mi = 0; mi < 4; ++mi)
#pragma unroll
      for (int ni = 0; ni < 4; ++ni)
        acc[mi][ni] = MFMA16x16(af[mi], bfv[ni], acc[mi][ni]);
    __syncthreads();
    buf ^= 1;
  }

  // C/D mapping: col = lane&15, row = (lane>>4)*4 + reg  [m89-verified]
  const int rbase = m0 + wr * 64 + (l >> 4) * 4;
  const int cbase = n0 + wc * 64 + (l & 15);
#pragma unroll
  for (int mi = 0; mi < 4; ++mi) {
#pragma unroll
    for (int ni = 0; ni < 4; ++ni) {
#pragma unroll
      for (int j = 0; j < 4; ++j) {
        const int row = rbase + mi * 16 + j;
        const int col = cbase + ni * 16;
        const float v = acc[mi][ni][j];
        if (EP == EP_BF16) {
          ((u16*)Cv)[(long)z * sCz + (long)row * ldc + col] = f2bf(v);
        } else if (EP == EP_PV) {
          if (col < 42) {
            const float iv = aux[z * 1024 + row];
            ((u16*)Cv)[(long)row * ldc + z * 42 + col] = f2bf(v * iv);
          }
        } else if (EP == EP_F32B) {
          ((float*)Cv)[(long)row * ldc + col] = v + bias[col];
        } else if (EP == EP_GELU) {
          const float tt = v + bias[col];
          const float g = 0.5f * tt * (1.0f + erff(tt * 0.70710678118654752f));
          ((u16*)Cv)[(long)row * ldc + col] = f2bf(g);
        } else if (EP == EP_OUT) {
          ((float*)Cv)[(long)row * ldc + col] =
              v + bias[col] + aux[(long)row * ldc + col];
        } else {  // EP_PART / EP_PVPART: raw f32 partial at slice z
          ((float*)Cv)[(long)z * sCz + (long)row * ldc + col] = v;
        }
      }
    }
  }
}

// out = p0 + p1 + b2 + fa  (f32x4 elementwise over [8192][512])
__global__ void combine_mlp2_kernel(const float* __restrict__ p,
                                    const float* __restrict__ fa,
                                    const float* __restrict__ b2,
                                    float* __restrict__ out) {
  const long i = (long)blockIdx.x * 256 + threadIdx.x;  // f32x4 index
  const f32x4 a = ((const f32x4*)p)[i];
  const f32x4 b = ((const f32x4*)(p + 8192L * 512))[i];
  const f32x4 f = ((const f32x4*)fa)[i];
  const f32x4 bb = ((const f32x4*)b2)[i & 127];
  ((f32x4*)out)[i] = a + b + f + bb;
}

// PV combine: cat[row][h*42+e] = invl[h*1024+row] * sum_s part[(h*4+s)][row][e]
__global__ void combine_pv_kernel(const float* __restrict__ part,
                                  const float* __restrict__ invl,
                                  u16* __restrict__ cat) {
  const int blk = blockIdx.x;  // h*1024 + row
  const int h = blk >> 10;
  const int row = blk & 1023;
  const int e = threadIdx.x;   // 64 threads, keep e<42
  if (e >= 42) return;
  const long base = (long)(h * 4) * 131072 + row * 128 + e;
  float v = part[base] + part[base + 131072] + part[base + 2 * 131072] +
            part[base + 3 * 131072];
  cat[(long)row * 512 + h * 42 + e] = f2bf(v * invl[h * 1024 + row]);
}

// ---------------------------------------------------------------------------
// LayerNorm / softmax / prep kernels
// ---------------------------------------------------------------------------
__global__ void ln1_kernel(const float* __restrict__ x,
                           const float* __restrict__ gamma,
                           const float* __restrict__ beta,
                           u16* __restrict__ n1) {
  __shared__ float red[16];
  const int s = blockIdx.x;
  const int t = threadIdx.x;
  const float* row = x + (long)s * 512;
  const float v0 = row[t];
  const float v1 = row[t + 256];
  float sum = wred_sum(v0 + v1);
  float sq = wred_sum(v0 * v0 + v1 * v1);
  if ((t & 63) == 0) { red[t >> 6] = sum; red[8 + (t >> 6)] = sq; }
  __syncthreads();
  sum = red[0] + red[1] + red[2] + red[3];
  sq = red[8] + red[9] + red[10] + red[11];
  const float mu = sum * (1.0f / 512.0f);
  const float rstd = rsqrtf(sq * (1.0f / 512.0f) - mu * mu + 1e-5f);
  n1[(long)s * 512 + t] = f2bf((v0 - mu) * rstd * gamma[t] + beta[t]);
  n1[(long)s * 512 + t + 256] =
      f2bf((v1 - mu) * rstd * gamma[t + 256] + beta[t + 256]);
}

__global__ void ln2_kernel(const float* __restrict__ x,
                           const float* __restrict__ aproj,
                           const float* __restrict__ gamma,
                           const float* __restrict__ beta,
                           float* __restrict__ fa, u16* __restrict__ n2) {
  __shared__ float red[16];
  const int r = blockIdx.x;  // b*1024 + s
  const int t = threadIdx.x;
  const int s = r & 1023;
  const float* xr = x + (long)r * 512;
  const float* ar = aproj + (long)s * 512;
  const float v0 = xr[t] + ar[t];
  const float v1 = xr[t + 256] + ar[t + 256];
  fa[(long)r * 512 + t] = v0;
  fa[(long)r * 512 + t + 256] = v1;
  float sum = wred_sum(v0 + v1);
  float sq = wred_sum(v0 * v0 + v1 * v1);
  if ((t & 63) == 0) { red[t >> 6] = sum; red[8 + (t >> 6)] = sq; }
  __syncthreads();
  sum = red[0] + red[1] + red[2] + red[3];
  sq = red[8] + red[9] + red[10] + red[11];
  const float mu = sum * (1.0f / 512.0f);
  const float rstd = rsqrtf(sq * (1.0f / 512.0f) - mu * mu + 1e-5f);
  n2[(long)r * 512 + t] = f2bf((v0 - mu) * rstd * gamma[t] + beta[t]);
  n2[(long)r * 512 + t + 256] =
      f2bf((v1 - mu) * rstd * gamma[t + 256] + beta[t + 256]);
}

// in-place row softmax over bf16 scores [12*1024][1024]; stores 1/sum
__global__ void softmax_kernel(u16* __restrict__ SP, float* __restrict__ invl) {
  __shared__ float red[16];
  const long row = blockIdx.x;
  u16* p = SP + row * 1024;
  const int t = threadIdx.x;
  uint2 u = ((const uint2*)p)[t];
  const float s0 = bf2f((u16)(u.x & 0xffff));
  const float s1 = bf2f((u16)(u.x >> 16));
  const float s2 = bf2f((u16)(u.y & 0xffff));
  const float s3 = bf2f((u16)(u.y >> 16));
  float m = wred_max(fmaxf(fmaxf(s0, s1), fmaxf(s2, s3)));
  if ((t & 63) == 0) red[t >> 6] = m;
  __syncthreads();
  m = fmaxf(fmaxf(red[0], red[1]), fmaxf(red[2], red[3]));
  const float e0 = __expf(s0 - m), e1 = __expf(s1 - m);
  const float e2 = __expf(s2 - m), e3 = __expf(s3 - m);
  float sum = wred_sum(e0 + e1 + e2 + e3);
  if ((t & 63) == 0) red[8 + (t >> 6)] = sum;
  __syncthreads();
  sum = red[8] + red[9] + red[10] + red[11];
  if (t == 0) invl[row] = 1.0f / sum;
  uint2 o;
  o.x = (unsigned)f2bf(e0) | ((unsigned)f2bf(e1) << 16);
  o.y = (unsigned)f2bf(e2) | ((unsigned)f2bf(e3) << 16);
  ((uint2*)p)[t] = o;
}

__global__ void prep_qkv_kernel(const float* __restrict__ wq,
                                const float* __restrict__ wk,
                                u16* __restrict__ BtQKV, float scale) {
  const int i = blockIdx.x * 256 + threadIdx.x;
  const int n = i >> 9, d = i & 511;
  const int pq = n / 768;
  const int h = (n % 768) >> 6;
  const int e = n & 63;
  float v = 0.f;
  if (e < 42) {
    v = (pq ? wk : wq)[((long)h * 512 + d) * 42 + e];
    if (!pq) v *= scale;
  }
  BtQKV[i] = f2bf(v);
}
__global__ void prep_wvT_kernel(const float* __restrict__ wv,
                                u16* __restrict__ wvT) {
  const int i = blockIdx.x * 256 + threadIdx.x;
  const int r = i >> 9, d = i & 511;
  const int h = r >> 7, e = r & 127;
  wvT[i] = f2bf(e < 42 ? wv[((long)h * 512 + d) * 42 + e] : 0.f);
}

// LDS-tiled transpose: out[n][k] = bf16(in[k][n]); zero-fill k >= Kin.
// grid = (N/64, Kpad/64), block 256. Coalesced on both sides.
__global__ void transpose_bf16_kernel(const float* __restrict__ in,
                                      u16* __restrict__ out, int N, int Kin,
                                      int Kpad) {
  __shared__ float tile[64][65];
  const int n0 = blockIdx.x * 64;
  const int k0 = blockIdx.y * 64;
  const int t = threadIdx.x;
  const int tc = t & 63;
  const int tr = t >> 6;  // 0..3
#pragma unroll
  for (int r = 0; r < 16; ++r) {
    const int kr = tr * 16 + r;
    const int kg = k0 + kr;
    tile[kr][tc] = (kg < Kin) ? in[(long)kg * N + n0 + tc] : 0.f;
  }
  __syncthreads();
  const int nr0 = t >> 4;        // 0..15
  const int kc = (t & 15) * 4;   // 16 lanes x 8B = 128B contiguous per row
#pragma unroll
  for (int p = 0; p < 4; ++p) {
    const int nr = nr0 + p * 16;
    ushort4 v;
    v.x = f2bf(tile[kc + 0][nr]);
    v.y = f2bf(tile[kc + 1][nr]);
    v.z = f2bf(tile[kc + 2][nr]);
    v.w = f2bf(tile[kc + 3][nr]);
    *(ushort4*)&out[(long)(n0 + nr) * Kpad + k0 + kc] = v;
  }
}

__global__ void zero_u16_kernel(u16* __restrict__ p) {
  p[blockIdx.x * 256 + threadIdx.x] = 0;
}

// ---------------------------------------------------------------------------
extern "C" void kernel_launch(void* const* d_in, const int* in_sizes, int n_in,
                              void* d_out, int out_size, void* d_ws,
                              size_t ws_size, hipStream_t stream) {
  const float* x = (const float*)d_in[0];
  const float* wk = (const float*)d_in[1];   // wk before wq in dict order
  const float* wq = (const float*)d_in[2];
  const float* wv = (const float*)d_in[3];
  const float* w_proj = (const float*)d_in[4];
  const float* b_proj = (const float*)d_in[5];
  const float* gamma = (const float*)d_in[6];
  const float* beta = (const float*)d_in[7];
  const float* w1 = (const float*)d_in[8];
  const float* b1 = (const float*)d_in[9];
  const float* w2 = (const float*)d_in[10];
  const float* b2 = (const float*)d_in[11];

  char* base = (char*)d_ws;
  size_t off = 0;
  auto alloc = [&](size_t bytes) -> void* {
    void* p = base + off;
    off += (bytes + 255) & ~(size_t)255;
    return p;
  };
  // [n1..aproj) spans ~37 MB, dead by MLP2 -> split-K partials (33.6 MB)
  // alias offset 0 (set below).
  u16* n1 = (u16*)alloc(1024L * 512 * 2);        // LN1(x[0]) bf16
  u16* qkvc = (u16*)alloc(1024L * 1536 * 2);     // [s][(q|k) h e64] bf16
  u16* SP = (u16*)alloc(12L * 1024 * 1024 * 2);  // scores -> P, in-place
  u16* wvT = (u16*)alloc(1536L * 512 * 2);       // [h*128+e][d]
  u16* vt = (u16*)alloc(1536L * 1024 * 2);       // v^T [h*128+e][t]
  u16* cat = (u16*)alloc(1024L * 512 * 2);       // concat heads, pad->512
  float* aproj = (float*)alloc(1024L * 512 * 4); // attn @ w_proj + b_proj
  float* fa = (float*)alloc(8192L * 512 * 4);    // first_added, f32
  u16* n2 = (u16*)alloc(8192L * 512 * 2);        // LN2 bf16
  u16* hbuf = (u16*)alloc(8192L * 2048 * 2);     // gelu(mlp1) bf16
  u16* BtQKV = (u16*)alloc(1536L * 512 * 2);
  u16* BtP = (u16*)alloc(512L * 512 * 2);
  u16* Bt1 = (u16*)alloc(2048L * 512 * 2);
  u16* Bt2 = (u16*)alloc(512L * 2048 * 2);
  float* invl = (float*)alloc(12L * 1024 * 4);
  float* pvpart = (float*)alloc(48L * 1024 * 128 * 4);  // 24 MB PV partials
  float* part = (float*)d_ws;  // MLP2 partials, aliases n1..aproj (dead then)
  (void)ws_size; (void)in_sizes; (void)n_in; (void)out_size;

  const float scale = 0.15430334996209191f;  // 42^-0.5 folded into q weights

  prep_qkv_kernel<<<3072, 256, 0, stream>>>(wq, wk, BtQKV, scale);
  prep_wvT_kernel<<<3072, 256, 0, stream>>>(wv, wvT);
  // BtP[512][512] = w_proj^T (pad 504->512); Bt1[2048][512] = w1^T;
  // Bt2[512][2048] = w2^T  (tiled, coalesced transposes)
  transpose_bf16_kernel<<<dim3(8, 8), 256, 0, stream>>>(w_proj, BtP, 512, 504, 512);
  transpose_bf16_kernel<<<dim3(32, 8), 256, 0, stream>>>(w1, Bt1, 2048, 512, 512);
  transpose_bf16_kernel<<<dim3(8, 32), 256, 0, stream>>>(w2, Bt2, 512, 2048, 2048);
  zero_u16_kernel<<<2048, 256, 0, stream>>>(cat);
  ln1_kernel<<<1024, 256, 0, stream>>>(x, gamma, beta, n1);

  // q,k = n1 @ {wq*scale, wk}: [1024,1536], K=512
  gemm2<EP_BF16><<<dim3(8, 12, 1), 256, 0, stream>>>(
      n1, 512, 0, BtQKV, 512, 0, qkvc, 1536, 0, 512, nullptr, nullptr);
  // vt = wvT @ n1^T: [1536,1024], K=512
  gemm2<EP_BF16><<<dim3(12, 8, 1), 256, 0, stream>>>(
      wvT, 512, 0, n1, 512, 0, vt, 1024, 0, 512, nullptr, nullptr);
  // scores per head: q_h [1024,64] x k_h^T -> [1024,1024] bf16
  gemm2<EP_BF16><<<dim3(8, 8, 12), 256, 0, stream>>>(
      qkvc, 1536, 64, qkvc + 768, 1536, 64, SP, 1024, 1024L * 1024, 64,
      nullptr, nullptr);
  softmax_kernel<<<12288, 256, 0, stream>>>(SP, invl);
  // PV split-K=4: z = h*4+s, each K=256 -> f32 partials [48][1024][128]
  gemm2<EP_PVPART><<<dim3(8, 1, 48), 256, 0, stream>>>(
      SP, 1024, 1024L * 1024, vt, 1024, 128L * 1024, pvpart, 128,
      1024L * 128, 256, nullptr, nullptr);
  combine_pv_kernel<<<12288, 64, 0, stream>>>(pvpart, invl, cat);
  // attn_proj = concat @ w_proj + b_proj: [1024,512] f32
  gemm2<EP_F32B><<<dim3(8, 4, 1), 256, 0, stream>>>(
      cat, 512, 0, BtP, 512, 0, aproj, 512, 0, 512, b_proj, nullptr);
  ln2_kernel<<<8192, 256, 0, stream>>>(x, aproj, gamma, beta, fa, n2);
  // h = gelu(n2 @ w1 + b1): [8192,2048] bf16
  gemm2<EP_GELU><<<dim3(64, 16, 1), 256, 0, stream>>>(
      n2, 512, 0, Bt1, 512, 0, hbuf, 2048, 0, 512, b1, nullptr);
  // MLP2 split-K=2: partials = h @ w2 slices (z strides K by 1024)
  gemm2<EP_PART><<<dim3(64, 4, 2), 256, 0, stream>>>(
      hbuf, 2048, 1024, Bt2, 2048, 1024, part, 512, 8192L * 512, 1024,
      nullptr, nullptr);
  // out = p0 + p1 + b2 + fa
  combine_mlp2_kernel<<<4096, 256, 0, stream>>>(part, fa, b2, (float*)d_out);
}

// Round 5
// 180.718 us; speedup vs baseline: 1.1948x; 1.0243x over previous
//
#include <hip/hip_runtime.h>
#include <hip/hip_bf16.h>
#include <stdint.h>

// EncoderBlock: B=8, S=1024, D=512, H=12, HS=42 (padded to 64 for GEMM).
// Only batch 0's attention is used (reference quirk: attn[0] + x).

typedef unsigned short u16;
typedef __attribute__((ext_vector_type(8))) short short8;  // 8 bf16 = 4 VGPRs
typedef __attribute__((ext_vector_type(4))) float f32x4;

__device__ __forceinline__ u16 f2bf(float f) {
  union { float f; unsigned u; } x; x.f = f;
  return (u16)((x.u + 0x7FFFu + ((x.u >> 16) & 1u)) >> 16);  // RNE
}
__device__ __forceinline__ float bf2f(u16 u) {
  union { unsigned u; float f; } x; x.u = ((unsigned)u) << 16;
  return x.f;
}

// async global->LDS, 16B per lane; LDS dest is wave-uniform base + lane*16.
__device__ __forceinline__ void gload_lds16(const u16* g, u16* l) {
  __builtin_amdgcn_global_load_lds(
      (__attribute__((address_space(1))) void*)g,
      (__attribute__((address_space(3))) void*)l, 16, 0, 0);
}

__device__ __forceinline__ float wred_sum(float v) {
#pragma unroll
  for (int off = 32; off > 0; off >>= 1) v += __shfl_xor(v, off, 64);
  return v;
}
__device__ __forceinline__ float wred_max(float v) {
#pragma unroll
  for (int off = 32; off > 0; off >>= 1) v = fmaxf(v, __shfl_xor(v, off, 64));
  return v;
}

#define MFMA16x16(a, b, c) __builtin_amdgcn_mfma_f32_16x16x32_bf16(a, b, c, 0, 0, 0)

// ---------------------------------------------------------------------------
// GEMM: C[m][n] = sum_k A[m][k] * Bt[n][k]   (A,Bt bf16 row-major; Bt is B^T)
// 128x128 tile, BK=32, 4 waves (2x2), mfma_f32_16x16x32_bf16.
// 3-buffer LDS ring + counted vmcnt (T4): per iter
//   { vmcnt(4); s_barrier; stage tile t+2 -> ring[(t+2)%3];
//     ds_read frags from ring[t%3]; lgkmcnt(0); 16 MFMA }
// vmcnt(4) BEFORE the barrier guarantees every wave's tile-t loads are done
// chip-wide when any wave reads them; prefetches for t+1/t+2 stay in flight
// ACROSS the barrier (never drained to 0 in the loop). Buffer ring[t%3] is
// overwritten at iter t+1, after all waves' reads of it completed (lgkmcnt(0)
// before MFMA -> reads done before each wave reaches iter t+1's barrier).
// Linear staging/ds_read layout (r3): source swizzle cost > conflict cost.
// Epilogues: 0=bf16, 1=PV-scaled scatter, 2=f32+bias, 3=gelu->bf16,
//            4=f32+bias+resid, 5=f32 partial (split-K), 6=PV f32 partial.
// ---------------------------------------------------------------------------
enum { EP_BF16 = 0, EP_PV = 1, EP_F32B = 2, EP_GELU = 3, EP_OUT = 4,
       EP_PART = 5, EP_PVPART = 6 };

template <int EP>
__launch_bounds__(256, 3)
__global__ void gemm3(const u16* __restrict__ A, int lda, long sAz,
                      const u16* __restrict__ Bt, int ldb, long sBz,
                      void* __restrict__ Cv, int ldc, long sCz,
                      int K, const float* __restrict__ bias,
                      const float* __restrict__ aux) {
  __shared__ u16 lds[3][8192];  // ring: [A 128x32 | B 128x32] = 16KB each
  const int z = blockIdx.z;
  const u16* Ab;
  const u16* Bb;
  if (EP == EP_PVPART) {  // z = head*4 + kslice, kslice covers 256 of K
    Ab = A + (long)(z >> 2) * sAz + (z & 3) * 256;
    Bb = Bt + (long)(z >> 2) * sBz + (z & 3) * 256;
  } else {
    Ab = A + (long)z * sAz;
    Bb = Bt + (long)z * sBz;
  }
  const int m0 = blockIdx.x * 128;
  const int n0 = blockIdx.y * 128;
  const int tid = threadIdx.x;
  const int w = tid >> 6;
  const int l = tid & 63;
  const int wr = w >> 1;
  const int wc = w & 1;
  const int NT = K >> 5;  // always >= 2 here (K >= 64)

  f32x4 acc[4][4];
#pragma unroll
  for (int i = 0; i < 4; ++i)
#pragma unroll
    for (int j = 0; j < 4; ++j) acc[i][j] = (f32x4){0.f, 0.f, 0.f, 0.f};

  // staging (linear): wave w covers rows [w*32, w*32+32); lane -> row l>>2,
  // 16B granule l&3.
  const int srow = w * 32 + (l >> 2);
  const int sk = (l & 3) * 8;
  const u16* ga0 = Ab + (long)(m0 + srow) * lda + sk;
  const u16* ga1 = Ab + (long)(m0 + srow + 16) * lda + sk;
  const u16* gb0 = Bb + (long)(n0 + srow) * ldb + sk;
  const u16* gb1 = Bb + (long)(n0 + srow + 16) * ldb + sk;
  const int dA = w * 1024;         // A region [0,4096)
  const int dB = 4096 + w * 1024;  // B region [4096,8192)

  // fragment reads (linear): row = (l&15), k-granule = l>>4
  const int aoff = (wr * 64 + (l & 15)) * 32 + (l >> 4) * 8;
  const int boff = 4096 + (wc * 64 + (l & 15)) * 32 + (l >> 4) * 8;

  u16* r0 = &lds[0][0];
  u16* r1 = &lds[1][0];
  u16* r2 = &lds[2][0];

#define STAGE(dst, kt)                          \
  do {                                          \
    const int k0_ = (kt) * 32;                  \
    gload_lds16(ga0 + k0_, (dst) + dA);         \
    gload_lds16(ga1 + k0_, (dst) + dA + 512);   \
    gload_lds16(gb0 + k0_, (dst) + dB);         \
    gload_lds16(gb1 + k0_, (dst) + dB + 512);   \
  } while (0)

  // prologue: tiles 0 and 1 in flight (8 loads/wave outstanding)
  STAGE(r0, 0);
  STAGE(r1, 1);

  for (int t = 0; t < NT; ++t) {
    asm volatile("s_waitcnt vmcnt(4)" ::: "memory");  // tile t complete
    __builtin_amdgcn_s_barrier();
    __builtin_amdgcn_sched_barrier(0);
    int t2 = t + 2;
    if (t2 >= NT) t2 -= NT;  // wrap-stage keeps vmcnt counts uniform
    STAGE(r2, t2);
    short8 af[4], bfv[4];
#pragma unroll
    for (int mi = 0; mi < 4; ++mi)
      af[mi] = *(const short8*)&r0[aoff + mi * 16 * 32];
#pragma unroll
    for (int ni = 0; ni < 4; ++ni)
      bfv[ni] = *(const short8*)&r0[boff + ni * 16 * 32];
    asm volatile("s_waitcnt lgkmcnt(0)" ::: "memory");
    __builtin_amdgcn_sched_barrier(0);
#pragma unroll
    for (int mi = 0; mi < 4; ++mi)
#pragma unroll
      for (int ni = 0; ni < 4; ++ni)
        acc[mi][ni] = MFMA16x16(af[mi], bfv[ni], acc[mi][ni]);
    u16* tmp = r0; r0 = r1; r1 = r2; r2 = tmp;  // rotate ring
  }
  asm volatile("s_waitcnt vmcnt(0)" ::: "memory");  // drain wrap-stage loads
#undef STAGE

  // C/D mapping: col = lane&15, row = (lane>>4)*4 + reg  [m89-verified]
  const int rbase = m0 + wr * 64 + (l >> 4) * 4;
  const int cbase = n0 + wc * 64 + (l & 15);
#pragma unroll
  for (int mi = 0; mi < 4; ++mi) {
#pragma unroll
    for (int ni = 0; ni < 4; ++ni) {
#pragma unroll
      for (int j = 0; j < 4; ++j) {
        const int row = rbase + mi * 16 + j;
        const int col = cbase + ni * 16;
        const float v = acc[mi][ni][j];
        if (EP == EP_BF16) {
          ((u16*)Cv)[(long)z * sCz + (long)row * ldc + col] = f2bf(v);
        } else if (EP == EP_PV) {
          if (col < 42) {
            const float iv = aux[z * 1024 + row];
            ((u16*)Cv)[(long)row * ldc + z * 42 + col] = f2bf(v * iv);
          }
        } else if (EP == EP_F32B) {
          ((float*)Cv)[(long)row * ldc + col] = v + bias[col];
        } else if (EP == EP_GELU) {
          const float tt = v + bias[col];
          const float g = 0.5f * tt * (1.0f + erff(tt * 0.70710678118654752f));
          ((u16*)Cv)[(long)row * ldc + col] = f2bf(g);
        } else if (EP == EP_OUT) {
          ((float*)Cv)[(long)row * ldc + col] =
              v + bias[col] + aux[(long)row * ldc + col];
        } else {  // EP_PART / EP_PVPART: raw f32 partial at slice z
          ((float*)Cv)[(long)z * sCz + (long)row * ldc + col] = v;
        }
      }
    }
  }
}

// out = p0 + p1 + b2 + fa  (f32x4 elementwise over [8192][512])
__global__ void combine_mlp2_kernel(const float* __restrict__ p,
                                    const float* __restrict__ fa,
                                    const float* __restrict__ b2,
                                    float* __restrict__ out) {
  const long i = (long)blockIdx.x * 256 + threadIdx.x;  // f32x4 index
  const f32x4 a = ((const f32x4*)p)[i];
  const f32x4 b = ((const f32x4*)(p + 8192L * 512))[i];
  const f32x4 f = ((const f32x4*)fa)[i];
  const f32x4 bb = ((const f32x4*)b2)[i & 127];
  ((f32x4*)out)[i] = a + b + f + bb;
}

// PV combine: cat[row][h*42+e] = invl[h*1024+row] * sum_s part[(h*4+s)][row][e]
__global__ void combine_pv_kernel(const float* __restrict__ part,
                                  const float* __restrict__ invl,
                                  u16* __restrict__ cat) {
  const int blk = blockIdx.x;  // h*1024 + row
  const int h = blk >> 10;
  const int row = blk & 1023;
  const int e = threadIdx.x;   // 64 threads, keep e<42
  if (e >= 42) return;
  const long base = (long)(h * 4) * 131072 + row * 128 + e;
  float v = part[base] + part[base + 131072] + part[base + 2 * 131072] +
            part[base + 3 * 131072];
  cat[(long)row * 512 + h * 42 + e] = f2bf(v * invl[h * 1024 + row]);
}

// ---------------------------------------------------------------------------
// LayerNorm / softmax / prep kernels
// ---------------------------------------------------------------------------
__global__ void ln1_kernel(const float* __restrict__ x,
                           const float* __restrict__ gamma,
                           const float* __restrict__ beta,
                           u16* __restrict__ n1) {
  __shared__ float red[16];
  const int s = blockIdx.x;
  const int t = threadIdx.x;
  const float* row = x + (long)s * 512;
  const float v0 = row[t];
  const float v1 = row[t + 256];
  float sum = wred_sum(v0 + v1);
  float sq = wred_sum(v0 * v0 + v1 * v1);
  if ((t & 63) == 0) { red[t >> 6] = sum; red[8 + (t >> 6)] = sq; }
  __syncthreads();
  sum = red[0] + red[1] + red[2] + red[3];
  sq = red[8] + red[9] + red[10] + red[11];
  const float mu = sum * (1.0f / 512.0f);
  const float rstd = rsqrtf(sq * (1.0f / 512.0f) - mu * mu + 1e-5f);
  n1[(long)s * 512 + t] = f2bf((v0 - mu) * rstd * gamma[t] + beta[t]);
  n1[(long)s * 512 + t + 256] =
      f2bf((v1 - mu) * rstd * gamma[t + 256] + beta[t + 256]);
}

__global__ void ln2_kernel(const float* __restrict__ x,
                           const float* __restrict__ aproj,
                           const float* __restrict__ gamma,
                           const float* __restrict__ beta,
                           float* __restrict__ fa, u16* __restrict__ n2) {
  __shared__ float red[16];
  const int r = blockIdx.x;  // b*1024 + s
  const int t = threadIdx.x;
  const int s = r & 1023;
  const float* xr = x + (long)r * 512;
  const float* ar = aproj + (long)s * 512;
  const float v0 = xr[t] + ar[t];
  const float v1 = xr[t + 256] + ar[t + 256];
  fa[(long)r * 512 + t] = v0;
  fa[(long)r * 512 + t + 256] = v1;
  float sum = wred_sum(v0 + v1);
  float sq = wred_sum(v0 * v0 + v1 * v1);
  if ((t & 63) == 0) { red[t >> 6] = sum; red[8 + (t >> 6)] = sq; }
  __syncthreads();
  sum = red[0] + red[1] + red[2] + red[3];
  sq = red[8] + red[9] + red[10] + red[11];
  const float mu = sum * (1.0f / 512.0f);
  const float rstd = rsqrtf(sq * (1.0f / 512.0f) - mu * mu + 1e-5f);
  n2[(long)r * 512 + t] = f2bf((v0 - mu) * rstd * gamma[t] + beta[t]);
  n2[(long)r * 512 + t + 256] =
      f2bf((v1 - mu) * rstd * gamma[t + 256] + beta[t + 256]);
}

// in-place row softmax over bf16 scores [12*1024][1024]; stores 1/sum
__global__ void softmax_kernel(u16* __restrict__ SP, float* __restrict__ invl) {
  __shared__ float red[16];
  const long row = blockIdx.x;
  u16* p = SP + row * 1024;
  const int t = threadIdx.x;
  uint2 u = ((const uint2*)p)[t];
  const float s0 = bf2f((u16)(u.x & 0xffff));
  const float s1 = bf2f((u16)(u.x >> 16));
  const float s2 = bf2f((u16)(u.y & 0xffff));
  const float s3 = bf2f((u16)(u.y >> 16));
  float m = wred_max(fmaxf(fmaxf(s0, s1), fmaxf(s2, s3)));
  if ((t & 63) == 0) red[t >> 6] = m;
  __syncthreads();
  m = fmaxf(fmaxf(red[0], red[1]), fmaxf(red[2], red[3]));
  const float e0 = __expf(s0 - m), e1 = __expf(s1 - m);
  const float e2 = __expf(s2 - m), e3 = __expf(s3 - m);
  float sum = wred_sum(e0 + e1 + e2 + e3);
  if ((t & 63) == 0) red[8 + (t >> 6)] = sum;
  __syncthreads();
  sum = red[8] + red[9] + red[10] + red[11];
  if (t == 0) invl[row] = 1.0f / sum;
  uint2 o;
  o.x = (unsigned)f2bf(e0) | ((unsigned)f2bf(e1) << 16);
  o.y = (unsigned)f2bf(e2) | ((unsigned)f2bf(e3) << 16);
  ((uint2*)p)[t] = o;
}

__global__ void prep_qkv_kernel(const float* __restrict__ wq,
                                const float* __restrict__ wk,
                                u16* __restrict__ BtQKV, float scale) {
  const int i = blockIdx.x * 256 + threadIdx.x;
  const int n = i >> 9, d = i & 511;
  const int pq = n / 768;
  const int h = (n % 768) >> 6;
  const int e = n & 63;
  float v = 0.f;
  if (e < 42) {
    v = (pq ? wk : wq)[((long)h * 512 + d) * 42 + e];
    if (!pq) v *= scale;
  }
  BtQKV[i] = f2bf(v);
}
__global__ void prep_wvT_kernel(const float* __restrict__ wv,
                                u16* __restrict__ wvT) {
  const int i = blockIdx.x * 256 + threadIdx.x;
  const int r = i >> 9, d = i & 511;
  const int h = r >> 7, e = r & 127;
  wvT[i] = f2bf(e < 42 ? wv[((long)h * 512 + d) * 42 + e] : 0.f);
}

// LDS-tiled transpose: out[n][k] = bf16(in[k][n]); zero-fill k >= Kin.
// grid = (N/64, Kpad/64), block 256. Coalesced on both sides.
__global__ void transpose_bf16_kernel(const float* __restrict__ in,
                                      u16* __restrict__ out, int N, int Kin,
                                      int Kpad) {
  __shared__ float tile[64][65];
  const int n0 = blockIdx.x * 64;
  const int k0 = blockIdx.y * 64;
  const int t = threadIdx.x;
  const int tc = t & 63;
  const int tr = t >> 6;  // 0..3
#pragma unroll
  for (int r = 0; r < 16; ++r) {
    const int kr = tr * 16 + r;
    const int kg = k0 + kr;
    tile[kr][tc] = (kg < Kin) ? in[(long)kg * N + n0 + tc] : 0.f;
  }
  __syncthreads();
  const int nr0 = t >> 4;        // 0..15
  const int kc = (t & 15) * 4;   // 16 lanes x 8B = 128B contiguous per row
#pragma unroll
  for (int p = 0; p < 4; ++p) {
    const int nr = nr0 + p * 16;
    ushort4 v;
    v.x = f2bf(tile[kc + 0][nr]);
    v.y = f2bf(tile[kc + 1][nr]);
    v.z = f2bf(tile[kc + 2][nr]);
    v.w = f2bf(tile[kc + 3][nr]);
    *(ushort4*)&out[(long)(n0 + nr) * Kpad + k0 + kc] = v;
  }
}

__global__ void zero_u16_kernel(u16* __restrict__ p) {
  p[blockIdx.x * 256 + threadIdx.x] = 0;
}

// ---------------------------------------------------------------------------
extern "C" void kernel_launch(void* const* d_in, const int* in_sizes, int n_in,
                              void* d_out, int out_size, void* d_ws,
                              size_t ws_size, hipStream_t stream) {
  const float* x = (const float*)d_in[0];
  const float* wk = (const float*)d_in[1];   // wk before wq in dict order
  const float* wq = (const float*)d_in[2];
  const float* wv = (const float*)d_in[3];
  const float* w_proj = (const float*)d_in[4];
  const float* b_proj = (const float*)d_in[5];
  const float* gamma = (const float*)d_in[6];
  const float* beta = (const float*)d_in[7];
  const float* w1 = (const float*)d_in[8];
  const float* b1 = (const float*)d_in[9];
  const float* w2 = (const float*)d_in[10];
  const float* b2 = (const float*)d_in[11];

  char* base = (char*)d_ws;
  size_t off = 0;
  auto alloc = [&](size_t bytes) -> void* {
    void* p = base + off;
    off += (bytes + 255) & ~(size_t)255;
    return p;
  };
  // [n1..aproj) spans ~37 MB, dead by MLP2 -> split-K partials (33.6 MB)
  // alias offset 0 (set below).
  u16* n1 = (u16*)alloc(1024L * 512 * 2);        // LN1(x[0]) bf16
  u16* qkvc = (u16*)alloc(1024L * 1536 * 2);     // [s][(q|k) h e64] bf16
  u16* SP = (u16*)alloc(12L * 1024 * 1024 * 2);  // scores -> P, in-place
  u16* wvT = (u16*)alloc(1536L * 512 * 2);       // [h*128+e][d]
  u16* vt = (u16*)alloc(1536L * 1024 * 2);       // v^T [h*128+e][t]
  u16* cat = (u16*)alloc(1024L * 512 * 2);       // concat heads, pad->512
  float* aproj = (float*)alloc(1024L * 512 * 4); // attn @ w_proj + b_proj
  float* fa = (float*)alloc(8192L * 512 * 4);    // first_added, f32
  u16* n2 = (u16*)alloc(8192L * 512 * 2);        // LN2 bf16
  u16* hbuf = (u16*)alloc(8192L * 2048 * 2);     // gelu(mlp1) bf16
  u16* BtQKV = (u16*)alloc(1536L * 512 * 2);
  u16* BtP = (u16*)alloc(512L * 512 * 2);
  u16* Bt1 = (u16*)alloc(2048L * 512 * 2);
  u16* Bt2 = (u16*)alloc(512L * 2048 * 2);
  float* invl = (float*)alloc(12L * 1024 * 4);
  float* pvpart = (float*)alloc(48L * 1024 * 128 * 4);  // 24 MB PV partials
  float* part = (float*)d_ws;  // MLP2 partials, aliases n1..aproj (dead then)
  (void)ws_size; (void)in_sizes; (void)n_in; (void)out_size;

  const float scale = 0.15430334996209191f;  // 42^-0.5 folded into q weights

  prep_qkv_kernel<<<3072, 256, 0, stream>>>(wq, wk, BtQKV, scale);
  prep_wvT_kernel<<<3072, 256, 0, stream>>>(wv, wvT);
  transpose_bf16_kernel<<<dim3(8, 8), 256, 0, stream>>>(w_proj, BtP, 512, 504, 512);
  transpose_bf16_kernel<<<dim3(32, 8), 256, 0, stream>>>(w1, Bt1, 2048, 512, 512);
  transpose_bf16_kernel<<<dim3(8, 32), 256, 0, stream>>>(w2, Bt2, 512, 2048, 2048);
  zero_u16_kernel<<<2048, 256, 0, stream>>>(cat);
  ln1_kernel<<<1024, 256, 0, stream>>>(x, gamma, beta, n1);

  // q,k = n1 @ {wq*scale, wk}: [1024,1536], K=512
  gemm3<EP_BF16><<<dim3(8, 12, 1), 256, 0, stream>>>(
      n1, 512, 0, BtQKV, 512, 0, qkvc, 1536, 0, 512, nullptr, nullptr);
  // vt = wvT @ n1^T: [1536,1024], K=512
  gemm3<EP_BF16><<<dim3(12, 8, 1), 256, 0, stream>>>(
      wvT, 512, 0, n1, 512, 0, vt, 1024, 0, 512, nullptr, nullptr);
  // scores per head: q_h [1024,64] x k_h^T -> [1024,1024] bf16
  gemm3<EP_BF16><<<dim3(8, 8, 12), 256, 0, stream>>>(
      qkvc, 1536, 64, qkvc + 768, 1536, 64, SP, 1024, 1024L * 1024, 64,
      nullptr, nullptr);
  softmax_kernel<<<12288, 256, 0, stream>>>(SP, invl);
  // PV split-K=4: z = h*4+s, each K=256 -> f32 partials [48][1024][128]
  gemm3<EP_PVPART><<<dim3(8, 1, 48), 256, 0, stream>>>(
      SP, 1024, 1024L * 1024, vt, 1024, 128L * 1024, pvpart, 128,
      1024L * 128, 256, nullptr, nullptr);
  combine_pv_kernel<<<12288, 64, 0, stream>>>(pvpart, invl, cat);
  // attn_proj = concat @ w_proj + b_proj: [1024,512] f32
  gemm3<EP_F32B><<<dim3(8, 4, 1), 256, 0, stream>>>(
      cat, 512, 0, BtP, 512, 0, aproj, 512, 0, 512, b_proj, nullptr);
  ln2_kernel<<<8192, 256, 0, stream>>>(x, aproj, gamma, beta, fa, n2);
  // h = gelu(n2 @ w1 + b1): [8192,2048] bf16
  gemm3<EP_GELU><<<dim3(64, 16, 1), 256, 0, stream>>>(
      n2, 512, 0, Bt1, 512, 0, hbuf, 2048, 0, 512, b1, nullptr);
  // MLP2 split-K=2: partials = h @ w2 slices (z strides K by 1024)
  gemm3<EP_PART><<<dim3(64, 4, 2), 256, 0, stream>>>(
      hbuf, 2048, 1024, Bt2, 2048, 1024, part, 512, 8192L * 512, 1024,
      nullptr, nullptr);
  // out = p0 + p1 + b2 + fa
  combine_mlp2_kernel<<<4096, 256, 0, stream>>>(part, fa, b2, (float*)d_out);
}